// Round 10
// baseline (169.796 us; speedup 1.0000x reference)
//
#include <hip/hip_runtime.h>
#include <math.h>

// ===================== ROUND 10: DIAGNOSTIC ROUND =====================
// Both kernels run their steady-state loop multiple times (output rescaled
// exactly), pushing each dispatch above the ~46us harness-fill cutoff so
// rocprof's top-5 finally shows OUR counters. Timing will regress ~2x this
// round by design; revert multiplier to 1 next round.
// =====================================================================

constexpr int BATCH = 64;
constexpr int IN    = 1024;
constexpr int NN    = 2048;
constexpr int OUTF  = 1024;

constexpr float INV2PI = 0.15915494309189535f;  // 1/(2*pi)
constexpr float SQRT2  = 1.4142135623730951f;

// sin_t + cos_t = sqrt(2)*sin(theta + pi/4); LUT quantization dropped
// (absmax ~8 vs threshold 26.7). One fma + one v_sin per element.

template<int M>
__device__ __forceinline__ void butterfly(float* acc, int lane) {
    const bool hi = (lane & M) != 0;
#pragma unroll
    for (int j = 0; j < M; ++j) {
        const float send = hi ? acc[j] : acc[j + M];
        const float recv = __shfl_xor(send, M, 64);
        acc[j] = (hi ? acc[j + M] : acc[j]) + recv;
    }
    if constexpr (M > 1) butterfly<M / 2>(acc, lane);
}

// ---------------- Stage 1: interference (x2 internal passes) ----------------
// part[b][n] fp32 512KB transposed. Wave = (neuron, batch-half), K=1024.
// DIAG: 8 chunk-iterations instead of 4 (each x-chunk processed twice),
// acc ends at 2x -> store acc * (SQRT2*0.5).

__global__ __launch_bounds__(512)
__attribute__((amdgpu_waves_per_eu(4, 4)))
void k_interf(const float* __restrict__ x, const float* __restrict__ W,
              const float* __restrict__ B, float* __restrict__ part) {
    __shared__ float xs[2][32 * 256];   // double buffer, 2 x 32KB

    const int tid  = threadIdx.x;
    const int lane = tid & 63;
    const int wv   = __builtin_amdgcn_readfirstlane(tid >> 6);   // 0..7
    const int bid  = blockIdx.x;      // 512 blocks
    const int h    = bid & 1;
    const int n    = (bid >> 1) * 8 + wv;

    float4 iv2[4], bs2[4];
#pragma unroll
    for (int kc = 0; kc < 4; ++kc) {
        const float4 w4 = *(const float4*)&W[(size_t)n * IN + kc * 256 + 4 * lane];
        const float4 b4 = *(const float4*)&B[(size_t)n * IN + kc * 256 + 4 * lane];
        iv2[kc].x = INV2PI * __builtin_amdgcn_rcpf(1.0f + fabsf(w4.x));
        iv2[kc].y = INV2PI * __builtin_amdgcn_rcpf(1.0f + fabsf(w4.y));
        iv2[kc].z = INV2PI * __builtin_amdgcn_rcpf(1.0f + fabsf(w4.z));
        iv2[kc].w = INV2PI * __builtin_amdgcn_rcpf(1.0f + fabsf(w4.w));
        bs2[kc].x = fmaf(b4.x, INV2PI, 0.125f);
        bs2[kc].y = fmaf(b4.y, INV2PI, 0.125f);
        bs2[kc].z = fmaf(b4.z, INV2PI, 0.125f);
        bs2[kc].w = fmaf(b4.w, INV2PI, 0.125f);
    }

    const float* gx = x + (size_t)(h * 32) * IN;

#define STAGE(KC, P)                                                           \
    {                                                                          \
        _Pragma("unroll")                                                      \
        for (int rr = 0; rr < 4; ++rr) {                                       \
            const int r = wv * 4 + rr;                                         \
            __builtin_amdgcn_global_load_lds(                                  \
                (const __attribute__((address_space(1))) unsigned int*)        \
                    (gx + (size_t)r * IN + (KC) * 256 + 4 * lane),             \
                (__attribute__((address_space(3))) unsigned int*)              \
                    &xs[(P)][r * 256],                                         \
                16, 0, 0);                                                     \
        }                                                                      \
    }

    float acc[32];
#pragma unroll
    for (int j = 0; j < 32; ++j) acc[j] = 0.0f;

    STAGE(0, 0);
    __syncthreads();

#pragma unroll   // DIAG: 8 = 2 passes over the 4 chunks; indices (kci&3) constant
    for (int kci = 0; kci < 8; ++kci) {
        const int p = kci & 1;
        if (kci < 7) STAGE((kci + 1) & 3, 1 - p);

        const float4 iv = iv2[kci & 3], bs = bs2[kci & 3];
#pragma unroll
        for (int bb = 0; bb < 32; ++bb) {
            const float4 xv = *(const float4*)&xs[p][bb * 256 + 4 * lane];
            const float a0 = fmaf(xv.x, iv.x, bs.x);
            const float a1 = fmaf(xv.y, iv.y, bs.y);
            const float a2 = fmaf(xv.z, iv.z, bs.z);
            const float a3 = fmaf(xv.w, iv.w, bs.w);
            const float t0 = __builtin_amdgcn_sinf(a0);
            const float t1 = __builtin_amdgcn_sinf(a1);
            const float t2 = __builtin_amdgcn_sinf(a2);
            const float t3 = __builtin_amdgcn_sinf(a3);
            acc[bb] += (t0 + t1) + (t2 + t3);
        }
        __syncthreads();
    }
#undef STAGE

#pragma unroll
    for (int j = 0; j < 32; ++j) acc[j] += __shfl_xor(acc[j], 32, 64);
    butterfly<16>(acc, lane);

    if (lane < 32)   // acc holds 2x the sum -> scale by SQRT2/2
        part[(size_t)(h * 32 + lane) * NN + n] = acc[0] * (SQRT2 * 0.5f);
}

// ---------------- Stage 2: projection (x4 internal passes) ----------------
// R8 float4 variant (best measured). DIAG: 32 slab-iterations = 4 passes
// over the 8 slabs; accs end at 4x -> scale 0.25 (exact).

__global__ __launch_bounds__(256)
__attribute__((amdgpu_waves_per_eu(2, 2)))
void k_proj(const float* __restrict__ part, const float* __restrict__ ow,
            float* __restrict__ out) {
    const int tid  = threadIdx.x;
    const int lane = tid & 63;
    const int wv   = __builtin_amdgcn_readfirstlane(tid >> 6);
    const int bid  = blockIdx.x;              // 512 blocks
    const int g    = bid & 7;                 // XCD-local o-group
    const int inr  = bid >> 3;
    const int o0   = g * 128 + (inr & 7) * 16 + wv * 4;
    const int b0   = (inr >> 3) * 8;

    float4 acc[4][8];
#pragma unroll
    for (int o = 0; o < 4; ++o)
#pragma unroll
        for (int b = 0; b < 8; ++b) acc[o][b] = make_float4(0.f, 0.f, 0.f, 0.f);

#pragma unroll 4   // DIAG: 32 = 4 passes x 8 slabs
    for (int it = 0; it < 32; ++it) {
        const int nb = (it & 7) * 256 + lane * 4;
        float4 wrow[4], vrow[8];
#pragma unroll
        for (int o = 0; o < 4; ++o)
            wrow[o] = *(const float4*)&ow[(size_t)(o0 + o) * NN + nb];
#pragma unroll
        for (int b = 0; b < 8; ++b)
            vrow[b] = *(const float4*)&part[(size_t)(b0 + b) * NN + nb];
#pragma unroll
        for (int o = 0; o < 4; ++o)
#pragma unroll
            for (int b = 0; b < 8; ++b) {
                acc[o][b].x = fmaf(wrow[o].x, vrow[b].x, acc[o][b].x);
                acc[o][b].y = fmaf(wrow[o].y, vrow[b].y, acc[o][b].y);
                acc[o][b].z = fmaf(wrow[o].z, vrow[b].z, acc[o][b].z);
                acc[o][b].w = fmaf(wrow[o].w, vrow[b].w, acc[o][b].w);
            }
    }

    float accs[32];
#pragma unroll
    for (int o = 0; o < 4; ++o)
#pragma unroll
        for (int b = 0; b < 8; ++b)
            accs[o * 8 + b] =
                ((acc[o][b].x + acc[o][b].y) + (acc[o][b].z + acc[o][b].w)) * 0.25f;

#pragma unroll
    for (int j = 0; j < 32; ++j) accs[j] += __shfl_xor(accs[j], 32, 64);
    butterfly<16>(accs, lane);

    if (lane < 32)
        out[(size_t)(b0 + (lane & 7)) * OUTF + o0 + (lane >> 3)] = accs[0];
}

extern "C" void kernel_launch(void* const* d_in, const int* in_sizes, int n_in,
                              void* d_out, int out_size, void* d_ws, size_t ws_size,
                              hipStream_t stream) {
    const float* x  = (const float*)d_in[0];
    const float* W  = (const float*)d_in[1];
    const float* B  = (const float*)d_in[2];
    const float* ow = (const float*)d_in[3];
    float* out  = (float*)d_out;
    float* part = (float*)d_ws;    // 512 KB, [b][n] transposed

    k_interf<<<dim3(512), dim3(512), 0, stream>>>(x, W, B, part);
    k_proj  <<<dim3(512), dim3(256), 0, stream>>>(part, ow, out);
}

// Round 11
// 113.080 us; speedup vs baseline: 1.5016x; 1.5016x over previous
//
#include <hip/hip_runtime.h>
#include <math.h>

// Problem sizes (fixed by setup_inputs)
constexpr int BATCH = 64;
constexpr int IN    = 1024;
constexpr int NN    = 2048;   // num_neurons
constexpr int OUTF  = 1024;

constexpr float INV2PI = 0.15915494309189535f;  // 1/(2*pi)
constexpr float SQRT2  = 1.4142135623730951f;

// sin_t + cos_t = sqrt(2)*sin(theta + pi/4); LUT quantization dropped
// (absmax ~8 vs threshold 26.7). One fma + one v_sin per element.

template<int M>
__device__ __forceinline__ void butterfly(float* acc, int lane) {
    const bool hi = (lane & M) != 0;
#pragma unroll
    for (int j = 0; j < M; ++j) {
        const float send = hi ? acc[j] : acc[j + M];
        const float recv = __shfl_xor(send, M, 64);
        acc[j] = (hi ? acc[j + M] : acc[j]) + recv;
    }
    if constexpr (M > 1) butterfly<M / 2>(acc, lane);
}

// ---------------- Stage 1: interference ---------------- (control, R7 form)
// part[b][n] fp32 512KB transposed. Wave = (neuron, batch-half), K=1024.

__global__ __launch_bounds__(512)
__attribute__((amdgpu_waves_per_eu(4, 4)))
void k_interf(const float* __restrict__ x, const float* __restrict__ W,
              const float* __restrict__ B, float* __restrict__ part) {
    __shared__ float xs[2][32 * 256];   // double buffer, 2 x 32KB

    const int tid  = threadIdx.x;
    const int lane = tid & 63;
    const int wv   = __builtin_amdgcn_readfirstlane(tid >> 6);   // 0..7
    const int bid  = blockIdx.x;      // 512 blocks
    const int h    = bid & 1;
    const int n    = (bid >> 1) * 8 + wv;

    float4 iv2[4], bs2[4];
#pragma unroll
    for (int kc = 0; kc < 4; ++kc) {
        const float4 w4 = *(const float4*)&W[(size_t)n * IN + kc * 256 + 4 * lane];
        const float4 b4 = *(const float4*)&B[(size_t)n * IN + kc * 256 + 4 * lane];
        iv2[kc].x = INV2PI * __builtin_amdgcn_rcpf(1.0f + fabsf(w4.x));
        iv2[kc].y = INV2PI * __builtin_amdgcn_rcpf(1.0f + fabsf(w4.y));
        iv2[kc].z = INV2PI * __builtin_amdgcn_rcpf(1.0f + fabsf(w4.z));
        iv2[kc].w = INV2PI * __builtin_amdgcn_rcpf(1.0f + fabsf(w4.w));
        bs2[kc].x = fmaf(b4.x, INV2PI, 0.125f);
        bs2[kc].y = fmaf(b4.y, INV2PI, 0.125f);
        bs2[kc].z = fmaf(b4.z, INV2PI, 0.125f);
        bs2[kc].w = fmaf(b4.w, INV2PI, 0.125f);
    }

    const float* gx = x + (size_t)(h * 32) * IN;

#define STAGE(KC, P)                                                           \
    {                                                                          \
        _Pragma("unroll")                                                      \
        for (int rr = 0; rr < 4; ++rr) {                                       \
            const int r = wv * 4 + rr;                                         \
            __builtin_amdgcn_global_load_lds(                                  \
                (const __attribute__((address_space(1))) unsigned int*)        \
                    (gx + (size_t)r * IN + (KC) * 256 + 4 * lane),             \
                (__attribute__((address_space(3))) unsigned int*)              \
                    &xs[(P)][r * 256],                                         \
                16, 0, 0);                                                     \
        }                                                                      \
    }

    float acc[32];
#pragma unroll
    for (int j = 0; j < 32; ++j) acc[j] = 0.0f;

    STAGE(0, 0);
    __syncthreads();

#pragma unroll
    for (int kc = 0; kc < 4; ++kc) {
        const int p = kc & 1;
        if (kc < 3) STAGE(kc + 1, 1 - p);

        const float4 iv = iv2[kc], bs = bs2[kc];
#pragma unroll   // MUST be full: partial unroll -> dynamic acc idx -> scratch
        for (int bb = 0; bb < 32; ++bb) {
            const float4 xv = *(const float4*)&xs[p][bb * 256 + 4 * lane];
            const float a0 = fmaf(xv.x, iv.x, bs.x);
            const float a1 = fmaf(xv.y, iv.y, bs.y);
            const float a2 = fmaf(xv.z, iv.z, bs.z);
            const float a3 = fmaf(xv.w, iv.w, bs.w);
            const float t0 = __builtin_amdgcn_sinf(a0);
            const float t1 = __builtin_amdgcn_sinf(a1);
            const float t2 = __builtin_amdgcn_sinf(a2);
            const float t3 = __builtin_amdgcn_sinf(a3);
            acc[bb] += (t0 + t1) + (t2 + t3);
        }
        __syncthreads();
    }
#undef STAGE

#pragma unroll
    for (int j = 0; j < 32; ++j) acc[j] += __shfl_xor(acc[j], 32, 64);
    butterfly<16>(acc, lane);

    if (lane < 32)
        part[(size_t)(h * 32 + lane) * NN + n] = acc[0] * SQRT2;
}

// ---------------- Stage 2: projection ----------------
// out[b][o] = sum_n part[b][n] * ow[o][n]. Wave owns 4o x 4b, lane spans n.
// R11: tile shrunk from 4ox8b (acc=128 VGPR -> allocator's 128-reg tier
// SPILLED ~24MB/call; R10 diag: WRITE_SIZE 95MB@x4, VALUBusy 12%) to 4ox4b:
// acc 64 + operands 32 + addr ~ 115 VGPR < 128 -> spill impossible.
// 4096 waves (1024 blocks x 4), XCD-local o-group keeps 1MB ow + 0.5MB part
// per XCD < 4MB L2.

__global__ __launch_bounds__(256)
__attribute__((amdgpu_waves_per_eu(4, 4)))
void k_proj(const float* __restrict__ part, const float* __restrict__ ow,
            float* __restrict__ out) {
    const int tid  = threadIdx.x;
    const int lane = tid & 63;
    const int wv   = __builtin_amdgcn_readfirstlane(tid >> 6);
    const int bid  = blockIdx.x;              // 1024 blocks
    const int g    = bid & 7;                 // XCD-local o-group (8 x 128 o)
    const int inr  = bid >> 3;                // 0..127
    const int o0   = g * 128 + (inr & 31) * 4;            // wave's 4 o-rows
    const int b0   = ((inr >> 5) * 4 + wv) * 4;           // wave's 4 b-rows

    float4 acc[4][4];
#pragma unroll
    for (int o = 0; o < 4; ++o)
#pragma unroll
        for (int b = 0; b < 4; ++b) acc[o][b] = make_float4(0.f, 0.f, 0.f, 0.f);

#pragma unroll 2
    for (int it = 0; it < NN / 256; ++it) {   // 8 slabs of 256 n
        const int nb = it * 256 + lane * 4;
        float4 wrow[4], vrow[4];
#pragma unroll
        for (int o = 0; o < 4; ++o)
            wrow[o] = *(const float4*)&ow[(size_t)(o0 + o) * NN + nb];
#pragma unroll
        for (int b = 0; b < 4; ++b)
            vrow[b] = *(const float4*)&part[(size_t)(b0 + b) * NN + nb];
#pragma unroll
        for (int o = 0; o < 4; ++o)
#pragma unroll
            for (int b = 0; b < 4; ++b) {
                acc[o][b].x = fmaf(wrow[o].x, vrow[b].x, acc[o][b].x);
                acc[o][b].y = fmaf(wrow[o].y, vrow[b].y, acc[o][b].y);
                acc[o][b].z = fmaf(wrow[o].z, vrow[b].z, acc[o][b].z);
                acc[o][b].w = fmaf(wrow[o].w, vrow[b].w, acc[o][b].w);
            }
    }

    // horizontal: 16 scalars, accs[o*4+b]
    float accs[16];
#pragma unroll
    for (int o = 0; o < 4; ++o)
#pragma unroll
        for (int b = 0; b < 4; ++b)
            accs[o * 4 + b] = (acc[o][b].x + acc[o][b].y) + (acc[o][b].z + acc[o][b].w);

    // cross-lane sum: fold ^32 and ^16 (lanes then equivalent mod 16), then
    // butterfly<8> -> lane l<16 holds tile-element l's total
#pragma unroll
    for (int j = 0; j < 16; ++j) accs[j] += __shfl_xor(accs[j], 32, 64);
#pragma unroll
    for (int j = 0; j < 16; ++j) accs[j] += __shfl_xor(accs[j], 16, 64);
    butterfly<8>(accs, lane);

    if (lane < 16)   // j = o*4+b -> o = lane>>2, b = lane&3
        out[(size_t)(b0 + (lane & 3)) * OUTF + o0 + (lane >> 2)] = accs[0];
}

extern "C" void kernel_launch(void* const* d_in, const int* in_sizes, int n_in,
                              void* d_out, int out_size, void* d_ws, size_t ws_size,
                              hipStream_t stream) {
    const float* x  = (const float*)d_in[0];
    const float* W  = (const float*)d_in[1];
    const float* B  = (const float*)d_in[2];
    const float* ow = (const float*)d_in[3];
    float* out  = (float*)d_out;
    float* part = (float*)d_ws;    // 512 KB, [b][n] transposed

    k_interf<<<dim3(512), dim3(512), 0, stream>>>(x, W, B, part);
    k_proj  <<<dim3(1024), dim3(256), 0, stream>>>(part, ow, out);
}